// Round 12
// baseline (206.705 us; speedup 1.0000x reference)
//
#include <hip/hip_runtime.h>
#include <hip/hip_bf16.h>
#include <math.h>

#define N_NODES 50000
#define N_EDGES 800000
#define IN_CH 128
#define OUT_CH 64
#define BN_EPS 1e-5f
#define CAP 64  // max in-degree slots; P(deg>64) ~ e^-40 for 800k edges into 50k nodes

typedef __attribute__((ext_vector_type(8))) short short8;
typedef __attribute__((ext_vector_type(4))) float f32x4;

__device__ __forceinline__ float bf16u_to_f32(uint u) { return __uint_as_float(u << 16); }

__device__ __forceinline__ ushort f32_to_bf16(float f) {
    uint u = __float_as_uint(f);
    uint r = (u + 0x7fff + ((u >> 16) & 1)) >> 16;  // RNE
    return (ushort)r;
}

// ---------------- fill slot table: slot[d*CAP + pos] = src (ushort) ----------------
// 2 edges/thread via int2: two INDEPENDENT atomic round-trips in flight per thread (the
// kernel is atomic-latency bound, VALUBusy 0.24%); 1563 blocks keeps full residency.
// Plain stores: L2 merges scattered 2B stores (NT stores -> partial-line writebacks, 46MB).
__global__ void fill_slots_kernel(const int2* __restrict__ esrc2, const int2* __restrict__ edst2,
                                  int* __restrict__ cnt, ushort* __restrict__ slot, int E2) {
    int i = blockIdx.x * blockDim.x + threadIdx.x;
    if (i < E2) {
        int2 s = esrc2[i];
        int2 d = edst2[i];
        int p0 = atomicAdd(&cnt[d.x], 1);
        int p1 = atomicAdd(&cnt[d.y], 1);
        if (p0 < CAP) slot[d.x * CAP + p0] = (ushort)s.x;
        if (p1 < CAP) slot[d.y * CAP + p1] = (ushort)s.y;
    }
}

// ---------------- MFMA GEMM: hb[N,64](bf16) = bf16(x[N,128]) @ bf16(W[128,64]) * rsqrt(cnt+1) --
// dinv[src] folded into hb so the gather inner loop is a pure row-sum. Also WRITES dinv[row]
// (nn==0 lanes) for the gather. XPAD=136: odd 16B-granule stride -> ds_read_b128 conflict-free.
#define XPAD 136
__global__ __launch_bounds__(256) void gemm_mfma_kernel(const float* __restrict__ x,
                                                        const float* __restrict__ W,
                                                        const int* __restrict__ cnt,
                                                        ushort* __restrict__ hb,
                                                        float* __restrict__ dinv, int N) {
    __shared__ ushort xs[64 * XPAD];
    __shared__ ushort wt[64 * XPAD];   // W^T: wt[n][k]
    int t = threadIdx.x;
    int lane = t & 63;
    int w = t >> 6;
    int nn = lane & 15;
    int quad = lane >> 4;
    int row0 = blockIdx.x * 64;

    // W staging: 8 x float4 loads (vs 32 scalar) per thread
    const float4* W4 = (const float4*)W;
#pragma unroll
    for (int i = 0; i < 8; ++i) {
        int f4 = t + 256 * i;
        float4 v = W4[f4];
        int e0 = f4 * 4;
        int k = e0 >> 6;
        int n = e0 & 63;   // 4 consecutive n at the same k
        wt[(n + 0) * XPAD + k] = f32_to_bf16(v.x);
        wt[(n + 1) * XPAD + k] = f32_to_bf16(v.y);
        wt[(n + 2) * XPAD + k] = f32_to_bf16(v.z);
        wt[(n + 3) * XPAD + k] = f32_to_bf16(v.w);
    }
#pragma unroll
    for (int i = 0; i < 8; ++i) {
        int linear4 = t + 256 * i;
        int r = linear4 >> 5;
        int c4 = linear4 & 31;
        int gr = row0 + r; if (gr >= N) gr = N - 1;
        float4 v = *(const float4*)(x + (size_t)gr * IN_CH + c4 * 4);
        ushort u0 = f32_to_bf16(v.x), u1 = f32_to_bf16(v.y);
        ushort u2 = f32_to_bf16(v.z), u3 = f32_to_bf16(v.w);
        uint2 packed = make_uint2((uint)u0 | ((uint)u1 << 16), (uint)u2 | ((uint)u3 << 16));
        *(uint2*)&xs[r * XPAD + c4 * 4] = packed;
    }
    __syncthreads();

    short8 bfrag[4][4];
#pragma unroll
    for (int t2 = 0; t2 < 4; ++t2)
#pragma unroll
        for (int c = 0; c < 4; ++c)
            bfrag[t2][c] = *(const short8*)&wt[(16 * t2 + nn) * XPAD + 32 * c + quad * 8];

    f32x4 acc[4] = {{0.f, 0.f, 0.f, 0.f}, {0.f, 0.f, 0.f, 0.f},
                    {0.f, 0.f, 0.f, 0.f}, {0.f, 0.f, 0.f, 0.f}};
#pragma unroll
    for (int c = 0; c < 4; ++c) {
        short8 afrag = *(const short8*)&xs[(16 * w + nn) * XPAD + 32 * c + quad * 8];
#pragma unroll
        for (int t2 = 0; t2 < 4; ++t2)
            acc[t2] = __builtin_amdgcn_mfma_f32_16x16x32_bf16(afrag, bfrag[t2][c], acc[t2], 0, 0, 0);
    }

    int rbase = row0 + 16 * w + quad * 4;
    float dv[4];
#pragma unroll
    for (int r = 0; r < 4; ++r)
        dv[r] = (rbase + r < N) ? rsqrtf((float)(cnt[rbase + r] + 1)) : 0.f;
    if (nn == 0) {  // each row covered exactly once across (w,quad,r)
#pragma unroll
        for (int r = 0; r < 4; ++r)
            if (rbase + r < N) dinv[rbase + r] = dv[r];
    }
#pragma unroll
    for (int t2 = 0; t2 < 4; ++t2) {
#pragma unroll
        for (int r = 0; r < 4; ++r) {
            int row = rbase + r;
            if (row < N) hb[(size_t)row * OUT_CH + 16 * t2 + nn] = f32_to_bf16(acc[t2][r] * dv[r]);
        }
    }
}

// ---------------- fused gather: 8 groups x 8 lanes, uint4 row loads (8 edges/instr) ----------
// KNOWN-GOOD round-6/7 source (passed twice, 63.6us, VGPR 32). The sched_barrier(0) pin
// attempt caused NONDETERMINISTIC post-timing divergence (absmax 1.62): fencing between
// ISSUE(0) and a CONSUME in a different CFG region (loop skipped for deg<=15) perturbed
// waitcnt placement on the loop-skipped path. DO NOT re-add scheduling fences here.
// Item 0 = self-loop, items 1..m = slot entries; out-of-range items read zeroed row hb[N].
__global__ __launch_bounds__(256) void gather_fused_kernel(const int* __restrict__ cnt,
                                                           const ushort* __restrict__ slot,
                                                           const float* __restrict__ dinv,
                                                           const ushort* __restrict__ hb,
                                                           const float* __restrict__ bias,
                                                           float* __restrict__ out,
                                                           float* __restrict__ sums, int N) {
    int t = threadIdx.x;
    int lane = t & 63;
    int g = lane >> 3;
    int sub = lane & 7;
    // channel this lane owns after the reducing exchange (3-bit reversal of g)
    int cidx = 8 * sub + (((g & 1) << 2) | (g & 2) | ((g >> 2) & 1));
    int wid = (blockIdx.x * blockDim.x + t) >> 6;
    int nw = (gridDim.x * blockDim.x) >> 6;
    float bias_c = bias[cidx];
    float ssum = 0.f, ssq = 0.f;

#define ISSUE(J, H0, H1) do {                                              \
        int e0 = (J) + g, e1 = e0 + 8;                                     \
        int i0 = e0 - 1; i0 = (i0 < 0) ? 0 : i0;                           \
        int s0 = __shfl(sv, i0);                                           \
        int s1 = __shfl(sv, e1 - 1);                                       \
        s0 = (e0 == 0) ? d : s0;                                           \
        s0 = (e0 < M) ? s0 : N_NODES;                                      \
        s1 = (e1 < M) ? s1 : N_NODES;                                      \
        H0 = *(const uint4*)(hb + ((size_t)s0 << 6) + (sub << 3));         \
        H1 = *(const uint4*)(hb + ((size_t)s1 << 6) + (sub << 3));         \
    } while (0)

#define CONSUME(H)                                                          \
        a0 += __uint_as_float((H).x << 16); a1 += __uint_as_float((H).x & 0xffff0000u); \
        a2 += __uint_as_float((H).y << 16); a3 += __uint_as_float((H).y & 0xffff0000u); \
        a4 += __uint_as_float((H).z << 16); a5 += __uint_as_float((H).z & 0xffff0000u); \
        a6 += __uint_as_float((H).w << 16); a7 += __uint_as_float((H).w & 0xffff0000u);

    for (int d = wid; d < N; d += nw) {
        float dd = dinv[d];
        int m = cnt[d]; if (m > CAP) m = CAP;
        int M = m + 1;  // +1: self-loop at item 0
        int sv = __builtin_nontemporal_load(&slot[(size_t)d * CAP + lane]);

        float a0 = 0.f, a1 = 0.f, a2 = 0.f, a3 = 0.f;
        float a4 = 0.f, a5 = 0.f, a6 = 0.f, a7 = 0.f;

        uint4 h0, h1;
        ISSUE(0, h0, h1);
        for (int j = 16; j < M; j += 16) {
            uint4 n0, n1;
            ISSUE(j, n0, n1);           // next block's loads fly while we consume
            CONSUME(h0); CONSUME(h1);
            h0 = n0; h1 = n1;
        }
        CONSUME(h0); CONSUME(h1);

        // reducing exchange across the 8 groups: 3 xor rounds, ends with 1 channel/lane
        float b0, b1, b2, b3;
        {
            float s0 = a0 + __shfl_xor(a0, 8);
            float s1 = a1 + __shfl_xor(a1, 8);
            float s2 = a2 + __shfl_xor(a2, 8);
            float s3 = a3 + __shfl_xor(a3, 8);
            float s4 = a4 + __shfl_xor(a4, 8);
            float s5 = a5 + __shfl_xor(a5, 8);
            float s6 = a6 + __shfl_xor(a6, 8);
            float s7 = a7 + __shfl_xor(a7, 8);
            bool hi = (g & 1);
            b0 = hi ? s4 : s0; b1 = hi ? s5 : s1; b2 = hi ? s6 : s2; b3 = hi ? s7 : s3;
        }
        float c0, c1;
        {
            float s0 = b0 + __shfl_xor(b0, 16);
            float s1 = b1 + __shfl_xor(b1, 16);
            float s2 = b2 + __shfl_xor(b2, 16);
            float s3 = b3 + __shfl_xor(b3, 16);
            bool hi = (g & 2);
            c0 = hi ? s2 : s0; c1 = hi ? s3 : s1;
        }
        float total;
        {
            float s0 = c0 + __shfl_xor(c0, 32);
            float s1 = c1 + __shfl_xor(c1, 32);
            total = (g & 4) ? s1 : s0;
        }

        float v = tanhf(fmaf(dd, total, bias_c));
        out[(size_t)d * OUT_CH + cidx] = v;  // 64 lanes cover one contiguous 256B row
        ssum += v;
        ssq += v * v;
    }
#undef ISSUE
#undef CONSUME

    __shared__ float ls[256];
    __shared__ float ls2[256];
    ls[t] = ssum; ls2[t] = ssq;
    __syncthreads();
    if (t < 128) { ls[t] += ls[t + 128]; ls2[t] += ls2[t + 128]; }
    __syncthreads();
    if (t < 64) {
        // lane==t here, so cidx is this thread's channel; same-channel partials fold correctly
        atomicAdd(&sums[cidx], ls[t] + ls[t + 64]);
        atomicAdd(&sums[64 + cidx], ls2[t] + ls2[t + 64]);
    }
}

// ---------------- BN apply in place (float4) ----------------
__global__ __launch_bounds__(256) void bn_apply_kernel(float4* __restrict__ a,
                                                       const float* __restrict__ sums,
                                                       const float* __restrict__ gamma,
                                                       const float* __restrict__ beta, int total4) {
    int c0 = (threadIdx.x * 4) & 63;
    const float invN = 1.0f / (float)N_NODES;
    float4 scale, shift;
    {
        float m0 = sums[c0 + 0] * invN, m1 = sums[c0 + 1] * invN;
        float m2 = sums[c0 + 2] * invN, m3 = sums[c0 + 3] * invN;
        float v0 = sums[64 + c0 + 0] * invN - m0 * m0;
        float v1 = sums[64 + c0 + 1] * invN - m1 * m1;
        float v2 = sums[64 + c0 + 2] * invN - m2 * m2;
        float v3 = sums[64 + c0 + 3] * invN - m3 * m3;
        scale.x = gamma[c0 + 0] * rsqrtf(v0 + BN_EPS);
        scale.y = gamma[c0 + 1] * rsqrtf(v1 + BN_EPS);
        scale.z = gamma[c0 + 2] * rsqrtf(v2 + BN_EPS);
        scale.w = gamma[c0 + 3] * rsqrtf(v3 + BN_EPS);
        shift.x = beta[c0 + 0] - m0 * scale.x;
        shift.y = beta[c0 + 1] - m1 * scale.y;
        shift.z = beta[c0 + 2] - m2 * scale.z;
        shift.w = beta[c0 + 3] - m3 * scale.w;
    }
    int stride = gridDim.x * blockDim.x;
    for (int idx = blockIdx.x * blockDim.x + threadIdx.x; idx < total4; idx += stride) {
        float4 v = a[idx];
        v.x = v.x * scale.x + shift.x;
        v.y = v.y * scale.y + shift.y;
        v.z = v.z * scale.z + shift.z;
        v.w = v.w * scale.w + shift.w;
        a[idx] = v;
    }
}

extern "C" void kernel_launch(void* const* d_in, const int* in_sizes, int n_in,
                              void* d_out, int out_size, void* d_ws, size_t ws_size,
                              hipStream_t stream) {
    const float* x     = (const float*)d_in[0];
    const int*   eidx  = (const int*)d_in[1];   // [2, E] flat: src row then dst row
    const float* W     = (const float*)d_in[2];
    const float* bias  = (const float*)d_in[3];
    const float* gamma = (const float*)d_in[4];
    const float* beta  = (const float*)d_in[5];
    float* out = (float*)d_out;

    const int2* esrc2 = (const int2*)eidx;
    const int2* edst2 = (const int2*)(eidx + N_EDGES);

    // workspace layout -- hb FIRST so its 128B rows are cache-line aligned:
    // hb[(N+1)*64] bf16 (6.4MB, row N = zeros) | cnt[N] i32 | sums[128] f32 |
    // slot[N*CAP] ushort (256B-aligned, 6.4MB) | dinv[N] f32
    ushort* hb   = (ushort*)d_ws;
    int*   cnt   = (int*)(hb + (size_t)(N_NODES + 1) * OUT_CH);
    float* sums  = (float*)(cnt + N_NODES);
    ushort* slot = (ushort*)(((uintptr_t)(sums + 128) + 255) & ~(uintptr_t)255);
    float* dinv  = (float*)(slot + (size_t)N_NODES * CAP);

    // one memset covers hb pad row (last 128B of hb, contiguous with cnt) + cnt + sums
    size_t zero_span = (size_t)OUT_CH * 2 + (size_t)N_NODES * 4 + 128 * 4;
    hipMemsetAsync(hb + (size_t)N_NODES * OUT_CH, 0, zero_span, stream);
    fill_slots_kernel<<<(N_EDGES / 2 + 255) / 256, 256, 0, stream>>>(esrc2, edst2, cnt, slot, N_EDGES / 2);
    gemm_mfma_kernel<<<(N_NODES + 63) / 64, 256, 0, stream>>>(x, W, cnt, hb, dinv, N_NODES);
    gather_fused_kernel<<<2048, 256, 0, stream>>>(cnt, slot, dinv, hb, bias, out, sums, N_NODES);
    bn_apply_kernel<<<512, 256, 0, stream>>>((float4*)out, sums, gamma, beta, N_NODES * OUT_CH / 4);
}

// Round 13
// 200.889 us; speedup vs baseline: 1.0289x; 1.0289x over previous
//
#include <hip/hip_runtime.h>
#include <hip/hip_bf16.h>
#include <math.h>

#define N_NODES 50000
#define N_EDGES 800000
#define IN_CH 128
#define OUT_CH 64
#define BN_EPS 1e-5f
#define CAP 64  // max in-degree slots; P(deg>64) ~ e^-40 for 800k edges into 50k nodes

typedef __attribute__((ext_vector_type(8))) short short8;
typedef __attribute__((ext_vector_type(4))) float f32x4;

__device__ __forceinline__ float bf16u_to_f32(uint u) { return __uint_as_float(u << 16); }

__device__ __forceinline__ ushort f32_to_bf16(float f) {
    uint u = __float_as_uint(f);
    uint r = (u + 0x7fff + ((u >> 16) & 1)) >> 16;  // RNE
    return (ushort)r;
}

// ---------------- fill slot table: slot[d*CAP + pos] = src (ushort) ----------------
// 2 edges/thread via int2: two INDEPENDENT atomic round-trips in flight per thread;
// 1563 blocks keeps full residency. Plain stores: L2 merges scattered 2B stores.
__global__ void fill_slots_kernel(const int2* __restrict__ esrc2, const int2* __restrict__ edst2,
                                  int* __restrict__ cnt, ushort* __restrict__ slot, int E2) {
    int i = blockIdx.x * blockDim.x + threadIdx.x;
    if (i < E2) {
        int2 s = esrc2[i];
        int2 d = edst2[i];
        int p0 = atomicAdd(&cnt[d.x], 1);
        int p1 = atomicAdd(&cnt[d.y], 1);
        if (p0 < CAP) slot[d.x * CAP + p0] = (ushort)s.x;
        if (p1 < CAP) slot[d.y * CAP + p1] = (ushort)s.y;
    }
}

// ---------------- MFMA GEMM: hb[N,64](bf16) = bf16(x[N,128]) @ bf16(W[128,64]) * rsqrt(cnt+1) --
// dinv[src] folded into hb so the gather inner loop is a pure row-sum. Also WRITES dinv[row]
// (nn==0 lanes) for the gather. XPAD=136: odd 16B-granule stride -> ds_read_b128 conflict-free.
#define XPAD 136
__global__ __launch_bounds__(256) void gemm_mfma_kernel(const float* __restrict__ x,
                                                        const float* __restrict__ W,
                                                        const int* __restrict__ cnt,
                                                        ushort* __restrict__ hb,
                                                        float* __restrict__ dinv, int N) {
    __shared__ ushort xs[64 * XPAD];
    __shared__ ushort wt[64 * XPAD];   // W^T: wt[n][k]
    int t = threadIdx.x;
    int lane = t & 63;
    int w = t >> 6;
    int nn = lane & 15;
    int quad = lane >> 4;
    int row0 = blockIdx.x * 64;

    // W staging: 8 x float4 loads (vs 32 scalar) per thread
    const float4* W4 = (const float4*)W;
#pragma unroll
    for (int i = 0; i < 8; ++i) {
        int f4 = t + 256 * i;
        float4 v = W4[f4];
        int e0 = f4 * 4;
        int k = e0 >> 6;
        int n = e0 & 63;   // 4 consecutive n at the same k
        wt[(n + 0) * XPAD + k] = f32_to_bf16(v.x);
        wt[(n + 1) * XPAD + k] = f32_to_bf16(v.y);
        wt[(n + 2) * XPAD + k] = f32_to_bf16(v.z);
        wt[(n + 3) * XPAD + k] = f32_to_bf16(v.w);
    }
#pragma unroll
    for (int i = 0; i < 8; ++i) {
        int linear4 = t + 256 * i;
        int r = linear4 >> 5;
        int c4 = linear4 & 31;
        int gr = row0 + r; if (gr >= N) gr = N - 1;
        float4 v = *(const float4*)(x + (size_t)gr * IN_CH + c4 * 4);
        ushort u0 = f32_to_bf16(v.x), u1 = f32_to_bf16(v.y);
        ushort u2 = f32_to_bf16(v.z), u3 = f32_to_bf16(v.w);
        uint2 packed = make_uint2((uint)u0 | ((uint)u1 << 16), (uint)u2 | ((uint)u3 << 16));
        *(uint2*)&xs[r * XPAD + c4 * 4] = packed;
    }
    __syncthreads();

    short8 bfrag[4][4];
#pragma unroll
    for (int t2 = 0; t2 < 4; ++t2)
#pragma unroll
        for (int c = 0; c < 4; ++c)
            bfrag[t2][c] = *(const short8*)&wt[(16 * t2 + nn) * XPAD + 32 * c + quad * 8];

    f32x4 acc[4] = {{0.f, 0.f, 0.f, 0.f}, {0.f, 0.f, 0.f, 0.f},
                    {0.f, 0.f, 0.f, 0.f}, {0.f, 0.f, 0.f, 0.f}};
#pragma unroll
    for (int c = 0; c < 4; ++c) {
        short8 afrag = *(const short8*)&xs[(16 * w + nn) * XPAD + 32 * c + quad * 8];
#pragma unroll
        for (int t2 = 0; t2 < 4; ++t2)
            acc[t2] = __builtin_amdgcn_mfma_f32_16x16x32_bf16(afrag, bfrag[t2][c], acc[t2], 0, 0, 0);
    }

    int rbase = row0 + 16 * w + quad * 4;
    float dv[4];
#pragma unroll
    for (int r = 0; r < 4; ++r)
        dv[r] = (rbase + r < N) ? rsqrtf((float)(cnt[rbase + r] + 1)) : 0.f;
    if (nn == 0) {  // each row covered exactly once across (w,quad,r)
#pragma unroll
        for (int r = 0; r < 4; ++r)
            if (rbase + r < N) dinv[rbase + r] = dv[r];
    }
#pragma unroll
    for (int t2 = 0; t2 < 4; ++t2) {
#pragma unroll
        for (int r = 0; r < 4; ++r) {
            int row = rbase + r;
            if (row < N) hb[(size_t)row * OUT_CH + 16 * t2 + nn] = f32_to_bf16(acc[t2][r] * dv[r]);
        }
    }
}

// 8-value cross-group reducing exchange (3 xor rounds); returns this lane's channel total.
__device__ __forceinline__ float reduce_groups(float a0, float a1, float a2, float a3,
                                               float a4, float a5, float a6, float a7, int g) {
    float s0 = a0 + __shfl_xor(a0, 8);
    float s1 = a1 + __shfl_xor(a1, 8);
    float s2 = a2 + __shfl_xor(a2, 8);
    float s3 = a3 + __shfl_xor(a3, 8);
    float s4 = a4 + __shfl_xor(a4, 8);
    float s5 = a5 + __shfl_xor(a5, 8);
    float s6 = a6 + __shfl_xor(a6, 8);
    float s7 = a7 + __shfl_xor(a7, 8);
    bool h1 = (g & 1);
    float b0 = h1 ? s4 : s0, b1 = h1 ? s5 : s1, b2 = h1 ? s6 : s2, b3 = h1 ? s7 : s3;
    float u0 = b0 + __shfl_xor(b0, 16);
    float u1 = b1 + __shfl_xor(b1, 16);
    float u2 = b2 + __shfl_xor(b2, 16);
    float u3 = b3 + __shfl_xor(b3, 16);
    bool h2 = (g & 2);
    float c0 = h2 ? u2 : u0, c1 = h2 ? u3 : u1;
    float v0 = c0 + __shfl_xor(c0, 32);
    float v1 = c1 + __shfl_xor(c1, 32);
    return (g & 4) ? v1 : v0;
}

// ---------------- fused gather: 2 NODES PER WAVE, 8 groups x 8 lanes, uint4 row loads --------
// The compiler persistently picks a 1-deep, 32-VGPR schedule for the single-node loop
// (64us, VALUBusy 16%) regardless of source framing -- so the ILP is now ARCHITECTURAL:
// two fully independent per-node chains (slot loads, h-streams, accumulators) fused in one
// loop over max(M0,M1). Shorter chain reads the zeroed pad row hb[N]; +0.0f is exact, so
// results are bit-identical. Up to 8 h-loads + 2 slot loads in flight per wave.
__global__ __launch_bounds__(256) void gather_fused_kernel(const int* __restrict__ cnt,
                                                           const ushort* __restrict__ slot,
                                                           const float* __restrict__ dinv,
                                                           const ushort* __restrict__ hb,
                                                           const float* __restrict__ bias,
                                                           float* __restrict__ out,
                                                           float* __restrict__ sums, int N) {
    int t = threadIdx.x;
    int lane = t & 63;
    int g = lane >> 3;
    int sub = lane & 7;
    // channel this lane owns after the reducing exchange (3-bit reversal of g)
    int cidx = 8 * sub + (((g & 1) << 2) | (g & 2) | ((g >> 2) & 1));
    int wid = (blockIdx.x * blockDim.x + t) >> 6;
    int nw = (gridDim.x * blockDim.x) >> 6;
    float bias_c = bias[cidx];
    float ssum = 0.f, ssq = 0.f;

#define ISSUE(SV, MM, DN, J, H0, H1) do {                                  \
        int e0 = (J) + g, e1 = e0 + 8;                                     \
        int i0 = e0 - 1; i0 = (i0 < 0) ? 0 : i0;                           \
        int s0 = __shfl(SV, i0);                                           \
        int s1 = __shfl(SV, e1 - 1);                                       \
        s0 = (e0 == 0) ? (DN) : s0;                                        \
        s0 = (e0 < (MM)) ? s0 : N_NODES;                                   \
        s1 = (e1 < (MM)) ? s1 : N_NODES;                                   \
        H0 = *(const uint4*)(hb + ((size_t)s0 << 6) + (sub << 3));         \
        H1 = *(const uint4*)(hb + ((size_t)s1 << 6) + (sub << 3));         \
    } while (0)

#define CONS_A(H)                                                           \
        aA0 += __uint_as_float((H).x << 16); aA1 += __uint_as_float((H).x & 0xffff0000u); \
        aA2 += __uint_as_float((H).y << 16); aA3 += __uint_as_float((H).y & 0xffff0000u); \
        aA4 += __uint_as_float((H).z << 16); aA5 += __uint_as_float((H).z & 0xffff0000u); \
        aA6 += __uint_as_float((H).w << 16); aA7 += __uint_as_float((H).w & 0xffff0000u);

#define CONS_B(H)                                                           \
        aB0 += __uint_as_float((H).x << 16); aB1 += __uint_as_float((H).x & 0xffff0000u); \
        aB2 += __uint_as_float((H).y << 16); aB3 += __uint_as_float((H).y & 0xffff0000u); \
        aB4 += __uint_as_float((H).z << 16); aB5 += __uint_as_float((H).z & 0xffff0000u); \
        aB6 += __uint_as_float((H).w << 16); aB7 += __uint_as_float((H).w & 0xffff0000u);

    for (int dA = wid; dA < N; dA += 2 * nw) {
        int dB = dA + nw;
        bool hasB = dB < N;
        int dBc = hasB ? dB : dA;  // clamped for safe (discarded) loads

        float ddA = dinv[dA];
        float ddB = dinv[dBc];
        int mA = cnt[dA]; if (mA > CAP) mA = CAP;
        int mB = cnt[dBc]; if (mB > CAP) mB = CAP;
        int svA = __builtin_nontemporal_load(&slot[(size_t)dA * CAP + lane]);
        int svB = __builtin_nontemporal_load(&slot[(size_t)dBc * CAP + lane]);
        int MA = mA + 1;
        int MB = hasB ? mB + 1 : 0;   // B disabled -> all its items hit pad row
        int Mmax = (MA > MB) ? MA : MB;

        float aA0 = 0.f, aA1 = 0.f, aA2 = 0.f, aA3 = 0.f;
        float aA4 = 0.f, aA5 = 0.f, aA6 = 0.f, aA7 = 0.f;
        float aB0 = 0.f, aB1 = 0.f, aB2 = 0.f, aB3 = 0.f;
        float aB4 = 0.f, aB5 = 0.f, aB6 = 0.f, aB7 = 0.f;

        uint4 hA0, hA1, hB0, hB1;
        ISSUE(svA, MA, dA, 0, hA0, hA1);
        ISSUE(svB, MB, dBc, 0, hB0, hB1);
        for (int j = 16; j < Mmax; j += 16) {
            uint4 nA0, nA1, nB0, nB1;
            ISSUE(svA, MA, dA, j, nA0, nA1);
            ISSUE(svB, MB, dBc, j, nB0, nB1);
            CONS_A(hA0); CONS_A(hA1);
            CONS_B(hB0); CONS_B(hB1);
            hA0 = nA0; hA1 = nA1; hB0 = nB0; hB1 = nB1;
        }
        CONS_A(hA0); CONS_A(hA1);
        CONS_B(hB0); CONS_B(hB1);

        float totalA = reduce_groups(aA0, aA1, aA2, aA3, aA4, aA5, aA6, aA7, g);
        float totalB = reduce_groups(aB0, aB1, aB2, aB3, aB4, aB5, aB6, aB7, g);

        float vA = tanhf(fmaf(ddA, totalA, bias_c));
        out[(size_t)dA * OUT_CH + cidx] = vA;
        ssum += vA;
        ssq += vA * vA;
        if (hasB) {
            float vB = tanhf(fmaf(ddB, totalB, bias_c));
            out[(size_t)dB * OUT_CH + cidx] = vB;
            ssum += vB;
            ssq += vB * vB;
        }
    }
#undef ISSUE
#undef CONS_A
#undef CONS_B

    __shared__ float ls[256];
    __shared__ float ls2[256];
    ls[t] = ssum; ls2[t] = ssq;
    __syncthreads();
    if (t < 128) { ls[t] += ls[t + 128]; ls2[t] += ls2[t + 128]; }
    __syncthreads();
    if (t < 64) {
        // lane==t here, so cidx is this thread's channel; same-channel partials fold correctly
        atomicAdd(&sums[cidx], ls[t] + ls[t + 64]);
        atomicAdd(&sums[64 + cidx], ls2[t] + ls2[t + 64]);
    }
}

// ---------------- BN apply in place (float4) ----------------
__global__ __launch_bounds__(256) void bn_apply_kernel(float4* __restrict__ a,
                                                       const float* __restrict__ sums,
                                                       const float* __restrict__ gamma,
                                                       const float* __restrict__ beta, int total4) {
    int c0 = (threadIdx.x * 4) & 63;
    const float invN = 1.0f / (float)N_NODES;
    float4 scale, shift;
    {
        float m0 = sums[c0 + 0] * invN, m1 = sums[c0 + 1] * invN;
        float m2 = sums[c0 + 2] * invN, m3 = sums[c0 + 3] * invN;
        float v0 = sums[64 + c0 + 0] * invN - m0 * m0;
        float v1 = sums[64 + c0 + 1] * invN - m1 * m1;
        float v2 = sums[64 + c0 + 2] * invN - m2 * m2;
        float v3 = sums[64 + c0 + 3] * invN - m3 * m3;
        scale.x = gamma[c0 + 0] * rsqrtf(v0 + BN_EPS);
        scale.y = gamma[c0 + 1] * rsqrtf(v1 + BN_EPS);
        scale.z = gamma[c0 + 2] * rsqrtf(v2 + BN_EPS);
        scale.w = gamma[c0 + 3] * rsqrtf(v3 + BN_EPS);
        shift.x = beta[c0 + 0] - m0 * scale.x;
        shift.y = beta[c0 + 1] - m1 * scale.y;
        shift.z = beta[c0 + 2] - m2 * scale.z;
        shift.w = beta[c0 + 3] - m3 * scale.w;
    }
    int stride = gridDim.x * blockDim.x;
    for (int idx = blockIdx.x * blockDim.x + threadIdx.x; idx < total4; idx += stride) {
        float4 v = a[idx];
        v.x = v.x * scale.x + shift.x;
        v.y = v.y * scale.y + shift.y;
        v.z = v.z * scale.z + shift.z;
        v.w = v.w * scale.w + shift.w;
        a[idx] = v;
    }
}

extern "C" void kernel_launch(void* const* d_in, const int* in_sizes, int n_in,
                              void* d_out, int out_size, void* d_ws, size_t ws_size,
                              hipStream_t stream) {
    const float* x     = (const float*)d_in[0];
    const int*   eidx  = (const int*)d_in[1];   // [2, E] flat: src row then dst row
    const float* W     = (const float*)d_in[2];
    const float* bias  = (const float*)d_in[3];
    const float* gamma = (const float*)d_in[4];
    const float* beta  = (const float*)d_in[5];
    float* out = (float*)d_out;

    const int2* esrc2 = (const int2*)eidx;
    const int2* edst2 = (const int2*)(eidx + N_EDGES);

    // workspace layout -- hb FIRST so its 128B rows are cache-line aligned:
    // hb[(N+1)*64] bf16 (6.4MB, row N = zeros) | cnt[N] i32 | sums[128] f32 |
    // slot[N*CAP] ushort (256B-aligned, 6.4MB) | dinv[N] f32
    ushort* hb   = (ushort*)d_ws;
    int*   cnt   = (int*)(hb + (size_t)(N_NODES + 1) * OUT_CH);
    float* sums  = (float*)(cnt + N_NODES);
    ushort* slot = (ushort*)(((uintptr_t)(sums + 128) + 255) & ~(uintptr_t)255);
    float* dinv  = (float*)(slot + (size_t)N_NODES * CAP);

    // one memset covers hb pad row (last 128B of hb, contiguous with cnt) + cnt + sums
    size_t zero_span = (size_t)OUT_CH * 2 + (size_t)N_NODES * 4 + 128 * 4;
    hipMemsetAsync(hb + (size_t)N_NODES * OUT_CH, 0, zero_span, stream);
    fill_slots_kernel<<<(N_EDGES / 2 + 255) / 256, 256, 0, stream>>>(esrc2, edst2, cnt, slot, N_EDGES / 2);
    gemm_mfma_kernel<<<(N_NODES + 63) / 64, 256, 0, stream>>>(x, W, cnt, hb, dinv, N_NODES);
    gather_fused_kernel<<<2048, 256, 0, stream>>>(cnt, slot, dinv, hb, bias, out, sums, N_NODES);
    bn_apply_kernel<<<512, 256, 0, stream>>>((float4*)out, sums, gamma, beta, N_NODES * OUT_CH / 4);
}

// Round 21
// 199.683 us; speedup vs baseline: 1.0352x; 1.0060x over previous
//
#include <hip/hip_runtime.h>
#include <hip/hip_bf16.h>
#include <math.h>

#define N_NODES 50000
#define N_EDGES 800000
#define IN_CH 128
#define OUT_CH 64
#define BN_EPS 1e-5f
#define CAP 64  // max in-degree slots; P(deg>64) ~ e^-40 for 800k edges into 50k nodes

typedef __attribute__((ext_vector_type(8))) short short8;
typedef __attribute__((ext_vector_type(4))) float f32x4;

__device__ __forceinline__ float bf16u_to_f32(uint u) { return __uint_as_float(u << 16); }

__device__ __forceinline__ ushort f32_to_bf16(float f) {
    uint u = __float_as_uint(f);
    uint r = (u + 0x7fff + ((u >> 16) & 1)) >> 16;  // RNE
    return (ushort)r;
}

// ---------------- fill slot table: slot[d*CAP + pos] = src (ushort) ----------------
// 2 edges/thread via int2: two INDEPENDENT atomic round-trips in flight per thread;
// 1563 blocks keeps full residency. Plain stores: L2 merges scattered 2B stores.
__global__ void fill_slots_kernel(const int2* __restrict__ esrc2, const int2* __restrict__ edst2,
                                  int* __restrict__ cnt, ushort* __restrict__ slot, int E2) {
    int i = blockIdx.x * blockDim.x + threadIdx.x;
    if (i < E2) {
        int2 s = esrc2[i];
        int2 d = edst2[i];
        int p0 = atomicAdd(&cnt[d.x], 1);
        int p1 = atomicAdd(&cnt[d.y], 1);
        if (p0 < CAP) slot[d.x * CAP + p0] = (ushort)s.x;
        if (p1 < CAP) slot[d.y * CAP + p1] = (ushort)s.y;
    }
}

// ---------------- MFMA GEMM: hb[N,64](bf16) = bf16(x[N,128]) @ bf16(W[128,64]) * rsqrt(cnt+1) --
// dinv[src] folded into hb so the gather inner loop is a pure row-sum. Also WRITES dinv[row]
// (nn==0 lanes) for the gather. XPAD=136: odd 16B-granule stride -> ds_read_b128 conflict-free.
#define XPAD 136
__global__ __launch_bounds__(256) void gemm_mfma_kernel(const float* __restrict__ x,
                                                        const float* __restrict__ W,
                                                        const int* __restrict__ cnt,
                                                        ushort* __restrict__ hb,
                                                        float* __restrict__ dinv, int N) {
    __shared__ ushort xs[64 * XPAD];
    __shared__ ushort wt[64 * XPAD];   // W^T: wt[n][k]
    int t = threadIdx.x;
    int lane = t & 63;
    int w = t >> 6;
    int nn = lane & 15;
    int quad = lane >> 4;
    int row0 = blockIdx.x * 64;

    // W staging: 8 x float4 loads (vs 32 scalar) per thread
    const float4* W4 = (const float4*)W;
#pragma unroll
    for (int i = 0; i < 8; ++i) {
        int f4 = t + 256 * i;
        float4 v = W4[f4];
        int e0 = f4 * 4;
        int k = e0 >> 6;
        int n = e0 & 63;   // 4 consecutive n at the same k
        wt[(n + 0) * XPAD + k] = f32_to_bf16(v.x);
        wt[(n + 1) * XPAD + k] = f32_to_bf16(v.y);
        wt[(n + 2) * XPAD + k] = f32_to_bf16(v.z);
        wt[(n + 3) * XPAD + k] = f32_to_bf16(v.w);
    }
#pragma unroll
    for (int i = 0; i < 8; ++i) {
        int linear4 = t + 256 * i;
        int r = linear4 >> 5;
        int c4 = linear4 & 31;
        int gr = row0 + r; if (gr >= N) gr = N - 1;
        float4 v = *(const float4*)(x + (size_t)gr * IN_CH + c4 * 4);
        ushort u0 = f32_to_bf16(v.x), u1 = f32_to_bf16(v.y);
        ushort u2 = f32_to_bf16(v.z), u3 = f32_to_bf16(v.w);
        uint2 packed = make_uint2((uint)u0 | ((uint)u1 << 16), (uint)u2 | ((uint)u3 << 16));
        *(uint2*)&xs[r * XPAD + c4 * 4] = packed;
    }
    __syncthreads();

    short8 bfrag[4][4];
#pragma unroll
    for (int t2 = 0; t2 < 4; ++t2)
#pragma unroll
        for (int c = 0; c < 4; ++c)
            bfrag[t2][c] = *(const short8*)&wt[(16 * t2 + nn) * XPAD + 32 * c + quad * 8];

    f32x4 acc[4] = {{0.f, 0.f, 0.f, 0.f}, {0.f, 0.f, 0.f, 0.f},
                    {0.f, 0.f, 0.f, 0.f}, {0.f, 0.f, 0.f, 0.f}};
#pragma unroll
    for (int c = 0; c < 4; ++c) {
        short8 afrag = *(const short8*)&xs[(16 * w + nn) * XPAD + 32 * c + quad * 8];
#pragma unroll
        for (int t2 = 0; t2 < 4; ++t2)
            acc[t2] = __builtin_amdgcn_mfma_f32_16x16x32_bf16(afrag, bfrag[t2][c], acc[t2], 0, 0, 0);
    }

    int rbase = row0 + 16 * w + quad * 4;
    float dv[4];
#pragma unroll
    for (int r = 0; r < 4; ++r)
        dv[r] = (rbase + r < N) ? rsqrtf((float)(cnt[rbase + r] + 1)) : 0.f;
    if (nn == 0) {  // each row covered exactly once across (w,quad,r)
#pragma unroll
        for (int r = 0; r < 4; ++r)
            if (rbase + r < N) dinv[rbase + r] = dv[r];
    }
#pragma unroll
    for (int t2 = 0; t2 < 4; ++t2) {
#pragma unroll
        for (int r = 0; r < 4; ++r) {
            int row = rbase + r;
            if (row < N) hb[(size_t)row * OUT_CH + 16 * t2 + nn] = f32_to_bf16(acc[t2][r] * dv[r]);
        }
    }
}

// 8-value cross-group reducing exchange (3 xor rounds); returns this lane's channel total.
__device__ __forceinline__ float reduce_groups(float a0, float a1, float a2, float a3,
                                               float a4, float a5, float a6, float a7, int g) {
    float s0 = a0 + __shfl_xor(a0, 8);
    float s1 = a1 + __shfl_xor(a1, 8);
    float s2 = a2 + __shfl_xor(a2, 8);
    float s3 = a3 + __shfl_xor(a3, 8);
    float s4 = a4 + __shfl_xor(a4, 8);
    float s5 = a5 + __shfl_xor(a5, 8);
    float s6 = a6 + __shfl_xor(a6, 8);
    float s7 = a7 + __shfl_xor(a7, 8);
    bool h1 = (g & 1);
    float b0 = h1 ? s4 : s0, b1 = h1 ? s5 : s1, b2 = h1 ? s6 : s2, b3 = h1 ? s7 : s3;
    float u0 = b0 + __shfl_xor(b0, 16);
    float u1 = b1 + __shfl_xor(b1, 16);
    float u2 = b2 + __shfl_xor(b2, 16);
    float u3 = b3 + __shfl_xor(b3, 16);
    bool h2 = (g & 2);
    float c0 = h2 ? u2 : u0, c1 = h2 ? u3 : u1;
    float v0 = c0 + __shfl_xor(c0, 32);
    float v1 = c1 + __shfl_xor(c1, 32);
    return (g & 4) ? v1 : v0;
}

// slot entry for local node k (half = (k&1)*32) position p, from preloaded dword register svj:
// dword (k*32 + p/2) of the wave's slot block lives in lane half + p/2 of svj (j = k>>1).
__device__ __forceinline__ int extract_slot(int svj, int half, int p) {
    uint r = (uint)__shfl(svj, half + (p >> 1));
    return (int)((r >> ((p & 1) * 16)) & 0xffffu);
}

// ---------------- fused gather: contiguous 6-7 nodes/wave, ALL slot data preloaded ----------
// Round-13 lesson: in-loop ILP (2-node pairs, VGPR 48) gained only 2.4us because each pair's
// chain HEAD (NT slot load + cnt + dinv, ~900cy, never overlapped across pairs) dominates.
// Now each wave owns a CONTIGUOUS node range (8192 waves x 6-7 nodes): its whole slot table
// (<=896B contiguous) is fetched by FOUR coalesced NT dword loads at wave start (sv0..sv3),
// cnt/dinv by one 8-lane load each. Per-node entries come from __shfl+half-extract of the
// preloaded regs -- after the preamble there are ZERO non-hb loads. Pairs statically
// unrolled (no runtime-indexed reg arrays). Per-node math bit-identical to round 13.
__global__ __launch_bounds__(256) void gather_fused_kernel(const int* __restrict__ cnt,
                                                           const ushort* __restrict__ slot,
                                                           const float* __restrict__ dinv,
                                                           const ushort* __restrict__ hb,
                                                           const float* __restrict__ bias,
                                                           float* __restrict__ out,
                                                           float* __restrict__ sums, int N) {
    int t = threadIdx.x;
    int lane = t & 63;
    int g = lane >> 3;
    int sub = lane & 7;
    // channel this lane owns after the reducing exchange (3-bit reversal of g)
    int cidx = 8 * sub + (((g & 1) << 2) | (g & 2) | ((g >> 2) & 1));
    int wv = (blockIdx.x * blockDim.x + t) >> 6;
    int nw = (gridDim.x * blockDim.x) >> 6;      // 8192
    float bias_c = bias[cidx];
    float ssum = 0.f, ssq = 0.f;

    // contiguous node range for this wave: first RR waves get RQ+1 nodes, rest RQ
    int RQ = N / nw;                              // 6
    int RR = N - RQ * nw;                         // 848
    int s = wv * RQ + (wv < RR ? wv : RR);
    int c = RQ + (wv < RR ? 1 : 0);               // 6 or 7

    // preload slot dwords for nodes s..s+7 (4 x 64-lane coalesced NT loads; tail reads spill
    // harmlessly into the adjacent dinv array -- values never consumed past node c-1)
    const int* sdw = (const int*)slot + (size_t)s * 32;
    int sv0 = __builtin_nontemporal_load(sdw + lane);
    int sv1 = __builtin_nontemporal_load(sdw + 64 + lane);
    int sv2 = __builtin_nontemporal_load(sdw + 128 + lane);
    int sv3 = __builtin_nontemporal_load(sdw + 192 + lane);
    // per-node meta: lane&7 -> node s+(lane&7); clamp for the last wave's tail
    int mi = s + (lane & 7); if (mi > N - 1) mi = N - 1;
    int mAll = cnt[mi];
    float dAll = dinv[mi];

#define ISSUE_N(SVJ, HALF, DN, MM, J, H0, H1) do {                         \
        int e0 = (J) + g, e1 = e0 + 8;                                     \
        int p0 = e0 - 1; p0 = (p0 < 0) ? 0 : p0;                           \
        int s0 = extract_slot(SVJ, HALF, p0);                              \
        int s1 = extract_slot(SVJ, HALF, e1 - 1);                          \
        s0 = (e0 == 0) ? (DN) : s0;                                        \
        s0 = (e0 < (MM)) ? s0 : N_NODES;                                   \
        s1 = (e1 < (MM)) ? s1 : N_NODES;                                   \
        H0 = *(const uint4*)(hb + ((size_t)s0 << 6) + (sub << 3));         \
        H1 = *(const uint4*)(hb + ((size_t)s1 << 6) + (sub << 3));         \
    } while (0)

#define CONS_A(H)                                                           \
        aA0 += __uint_as_float((H).x << 16); aA1 += __uint_as_float((H).x & 0xffff0000u); \
        aA2 += __uint_as_float((H).y << 16); aA3 += __uint_as_float((H).y & 0xffff0000u); \
        aA4 += __uint_as_float((H).z << 16); aA5 += __uint_as_float((H).z & 0xffff0000u); \
        aA6 += __uint_as_float((H).w << 16); aA7 += __uint_as_float((H).w & 0xffff0000u);

#define CONS_B(H)                                                           \
        aB0 += __uint_as_float((H).x << 16); aB1 += __uint_as_float((H).x & 0xffff0000u); \
        aB2 += __uint_as_float((H).y << 16); aB3 += __uint_as_float((H).y & 0xffff0000u); \
        aB4 += __uint_as_float((H).z << 16); aB5 += __uint_as_float((H).z & 0xffff0000u); \
        aB6 += __uint_as_float((H).w << 16); aB7 += __uint_as_float((H).w & 0xffff0000u);

#define PAIR(K, SVJ) do {                                                   \
        int dA = s + (K);                                                   \
        int dB = dA + 1;                                                    \
        int mA = __shfl(mAll, (K));     if (mA > CAP) mA = CAP;             \
        int mB = __shfl(mAll, (K) + 1); if (mB > CAP) mB = CAP;             \
        float ddA = __shfl(dAll, (K));                                      \
        float ddB = __shfl(dAll, (K) + 1);                                  \
        int MA = mA + 1, MB = mB + 1;                                       \
        int Mmax = (MA > MB) ? MA : MB;                                     \
        float aA0=0.f,aA1=0.f,aA2=0.f,aA3=0.f,aA4=0.f,aA5=0.f,aA6=0.f,aA7=0.f; \
        float aB0=0.f,aB1=0.f,aB2=0.f,aB3=0.f,aB4=0.f,aB5=0.f,aB6=0.f,aB7=0.f; \
        uint4 hA0, hA1, hB0, hB1;                                           \
        ISSUE_N(SVJ, 0,  dA, MA, 0, hA0, hA1);                              \
        ISSUE_N(SVJ, 32, dB, MB, 0, hB0, hB1);                              \
        for (int j = 16; j < Mmax; j += 16) {                               \
            uint4 nA0, nA1, nB0, nB1;                                       \
            ISSUE_N(SVJ, 0,  dA, MA, j, nA0, nA1);                          \
            ISSUE_N(SVJ, 32, dB, MB, j, nB0, nB1);                          \
            CONS_A(hA0); CONS_A(hA1); CONS_B(hB0); CONS_B(hB1);             \
            hA0 = nA0; hA1 = nA1; hB0 = nB0; hB1 = nB1;                     \
        }                                                                    \
        CONS_A(hA0); CONS_A(hA1); CONS_B(hB0); CONS_B(hB1);                 \
        float totalA = reduce_groups(aA0,aA1,aA2,aA3,aA4,aA5,aA6,aA7, g);   \
        float totalB = reduce_groups(aB0,aB1,aB2,aB3,aB4,aB5,aB6,aB7, g);   \
        float vA = tanhf(fmaf(ddA, totalA, bias_c));                        \
        float vB = tanhf(fmaf(ddB, totalB, bias_c));                        \
        out[(size_t)dA * OUT_CH + cidx] = vA;                               \
        out[(size_t)dB * OUT_CH + cidx] = vB;                               \
        ssum += vA + vB;                                                    \
        ssq += vA * vA + vB * vB;                                           \
    } while (0)

#define SINGLE(K, SVJ) do {                                                 \
        int dA = s + (K);                                                   \
        int mA = __shfl(mAll, (K)); if (mA > CAP) mA = CAP;                 \
        float ddA = __shfl(dAll, (K));                                      \
        int MA = mA + 1;                                                    \
        float aA0=0.f,aA1=0.f,aA2=0.f,aA3=0.f,aA4=0.f,aA5=0.f,aA6=0.f,aA7=0.f; \
        uint4 hA0, hA1;                                                     \
        ISSUE_N(SVJ, 0, dA, MA, 0, hA0, hA1);                               \
        for (int j = 16; j < MA; j += 16) {                                 \
            uint4 nA0, nA1;                                                 \
            ISSUE_N(SVJ, 0, dA, MA, j, nA0, nA1);                           \
            CONS_A(hA0); CONS_A(hA1);                                       \
            hA0 = nA0; hA1 = nA1;                                           \
        }                                                                    \
        CONS_A(hA0); CONS_A(hA1);                                           \
        float totalA = reduce_groups(aA0,aA1,aA2,aA3,aA4,aA5,aA6,aA7, g);   \
        float vA = tanhf(fmaf(ddA, totalA, bias_c));                        \
        out[(size_t)dA * OUT_CH + cidx] = vA;                               \
        ssum += vA;                                                         \
        ssq += vA * vA;                                                     \
    } while (0)

    PAIR(0, sv0);
    PAIR(2, sv1);
    PAIR(4, sv2);
    if (c == 7) { SINGLE(6, sv3); }

#undef ISSUE_N
#undef CONS_A
#undef CONS_B
#undef PAIR
#undef SINGLE

    __shared__ float ls[256];
    __shared__ float ls2[256];
    ls[t] = ssum; ls2[t] = ssq;
    __syncthreads();
    if (t < 128) { ls[t] += ls[t + 128]; ls2[t] += ls2[t + 128]; }
    __syncthreads();
    if (t < 64) {
        // lane==t here, so cidx is this thread's channel; same-channel partials fold correctly
        atomicAdd(&sums[cidx], ls[t] + ls[t + 64]);
        atomicAdd(&sums[64 + cidx], ls2[t] + ls2[t + 64]);
    }
}

// ---------------- BN apply in place (float4) ----------------
__global__ __launch_bounds__(256) void bn_apply_kernel(float4* __restrict__ a,
                                                       const float* __restrict__ sums,
                                                       const float* __restrict__ gamma,
                                                       const float* __restrict__ beta, int total4) {
    int c0 = (threadIdx.x * 4) & 63;
    const float invN = 1.0f / (float)N_NODES;
    float4 scale, shift;
    {
        float m0 = sums[c0 + 0] * invN, m1 = sums[c0 + 1] * invN;
        float m2 = sums[c0 + 2] * invN, m3 = sums[c0 + 3] * invN;
        float v0 = sums[64 + c0 + 0] * invN - m0 * m0;
        float v1 = sums[64 + c0 + 1] * invN - m1 * m1;
        float v2 = sums[64 + c0 + 2] * invN - m2 * m2;
        float v3 = sums[64 + c0 + 3] * invN - m3 * m3;
        scale.x = gamma[c0 + 0] * rsqrtf(v0 + BN_EPS);
        scale.y = gamma[c0 + 1] * rsqrtf(v1 + BN_EPS);
        scale.z = gamma[c0 + 2] * rsqrtf(v2 + BN_EPS);
        scale.w = gamma[c0 + 3] * rsqrtf(v3 + BN_EPS);
        shift.x = beta[c0 + 0] - m0 * scale.x;
        shift.y = beta[c0 + 1] - m1 * scale.y;
        shift.z = beta[c0 + 2] - m2 * scale.z;
        shift.w = beta[c0 + 3] - m3 * scale.w;
    }
    int stride = gridDim.x * blockDim.x;
    for (int idx = blockIdx.x * blockDim.x + threadIdx.x; idx < total4; idx += stride) {
        float4 v = a[idx];
        v.x = v.x * scale.x + shift.x;
        v.y = v.y * scale.y + shift.y;
        v.z = v.z * scale.z + shift.z;
        v.w = v.w * scale.w + shift.w;
        a[idx] = v;
    }
}

extern "C" void kernel_launch(void* const* d_in, const int* in_sizes, int n_in,
                              void* d_out, int out_size, void* d_ws, size_t ws_size,
                              hipStream_t stream) {
    const float* x     = (const float*)d_in[0];
    const int*   eidx  = (const int*)d_in[1];   // [2, E] flat: src row then dst row
    const float* W     = (const float*)d_in[2];
    const float* bias  = (const float*)d_in[3];
    const float* gamma = (const float*)d_in[4];
    const float* beta  = (const float*)d_in[5];
    float* out = (float*)d_out;

    const int2* esrc2 = (const int2*)eidx;
    const int2* edst2 = (const int2*)(eidx + N_EDGES);

    // workspace layout -- hb FIRST so its 128B rows are cache-line aligned:
    // hb[(N+1)*64] bf16 (6.4MB, row N = zeros) | cnt[N] i32 | sums[128] f32 |
    // slot[N*CAP] ushort (256B-aligned, 6.4MB) | dinv[N] f32 (also absorbs slot tail reads)
    ushort* hb   = (ushort*)d_ws;
    int*   cnt   = (int*)(hb + (size_t)(N_NODES + 1) * OUT_CH);
    float* sums  = (float*)(cnt + N_NODES);
    ushort* slot = (ushort*)(((uintptr_t)(sums + 128) + 255) & ~(uintptr_t)255);
    float* dinv  = (float*)(slot + (size_t)N_NODES * CAP);

    // one memset covers hb pad row (last 128B of hb, contiguous with cnt) + cnt + sums
    size_t zero_span = (size_t)OUT_CH * 2 + (size_t)N_NODES * 4 + 128 * 4;
    hipMemsetAsync(hb + (size_t)N_NODES * OUT_CH, 0, zero_span, stream);
    fill_slots_kernel<<<(N_EDGES / 2 + 255) / 256, 256, 0, stream>>>(esrc2, edst2, cnt, slot, N_EDGES / 2);
    gemm_mfma_kernel<<<(N_NODES + 63) / 64, 256, 0, stream>>>(x, W, cnt, hb, dinv, N_NODES);
    gather_fused_kernel<<<2048, 256, 0, stream>>>(cnt, slot, dinv, hb, bias, out, sums, N_NODES);
    bn_apply_kernel<<<512, 256, 0, stream>>>((float4*)out, sums, gamma, beta, N_NODES * OUT_CH / 4);
}